// Round 6
// baseline (14404.427 us; speedup 1.0000x reference)
//
#include <hip/hip_runtime.h>
#include <hip/hip_bf16.h>
#include <hip/hip_cooperative_groups.h>
#include <math.h>

namespace cg = cooperative_groups;

#define B_   32
#define T_   64
#define N_   128
#define D_   64
#define C_   129
#define CK_  16
#define H_   2
#define QD_  5
#define PLM_ 768

// ---- workspace layout (float offsets, all float4-aligned) ----
constexpr int OFF_QV   = 0;                                   // 640
constexpr int OFF_WT   = 640;                                 // 3*128*64*132 Weff^T [g][n][o][cc pad132]
constexpr int OFF_BEFF = OFF_WT + 3*128*64*132;               // 3*128*64
constexpr int OFF_VWP  = OFF_BEFF + 3*128*64;                 // 2*129*132  v_W [h][cc][c pad132]
constexpr int OFF_QKT  = OFF_VWP + 2*129*132;                 // 2*2*16*132 qk_W^T [qk][h][ck][cc pad132]
constexpr int OFF_VTO  = OFF_QKT + 2*2*16*132;                // B*N
constexpr int OFF_KT   = OFF_VTO + B_*N_;                     // 2*B*H*N*CK [par][b][h][j][ck]
constexpr int OFF_VG   = OFF_KT + 2*B_*H_*N_*CK_;             // 2*B*H*N*132 [par][b][h][j][c pad132]
// end ~23.0 MB of d_ws

// ---------------- precompute kernels ----------------

__global__ void k_qv(const float* __restrict__ plm,
                     const float* __restrict__ W1,
                     const float* __restrict__ b1,
                     const float* __restrict__ W2,
                     const float* __restrict__ b2,
                     float* __restrict__ ws) {
    int n = blockIdx.x;            // 128 blocks
    int j = threadIdx.x;           // 128 threads
    __shared__ float hid[128];
    float acc = b1[j];
    for (int p = 0; p < PLM_; ++p)
        acc += plm[n*PLM_ + p] * W1[p*128 + j];
    hid[j] = fmaxf(acc, 0.f);
    __syncthreads();
    if (j < QD_) {
        float a = b2[j];
        for (int q = 0; q < 128; ++q) a += hid[q] * W2[q*QD_ + j];
        ws[OFF_QV + n*QD_ + j] = a;
    }
}

// WT[g][n][o][cc pad132] = sum_q qv[n,q]*W_g[q][cc][o];  beff[g][n][o]
__global__ void k_weff(const float* __restrict__ rW,
                       const float* __restrict__ uW,
                       const float* __restrict__ cW,
                       const float* __restrict__ rb,
                       const float* __restrict__ ub,
                       const float* __restrict__ cb,
                       float* __restrict__ ws) {
    int g = blockIdx.x >> 7;       // 3*128 blocks
    int n = blockIdx.x & 127;
    const float* W  = (g == 0) ? rW : (g == 1) ? uW : cW;
    const float* bb = (g == 0) ? rb : (g == 1) ? ub : cb;
    float qn[QD_];
#pragma unroll
    for (int q = 0; q < QD_; ++q) qn[q] = ws[OFF_QV + n*QD_ + q];
    for (int idx = threadIdx.x; idx < C_*D_; idx += 256) {
        int cc = idx >> 6, o = idx & 63;
        float acc = 0.f;
#pragma unroll
        for (int q = 0; q < QD_; ++q) acc += qn[q] * W[(q*C_ + cc)*D_ + o];
        ws[OFF_WT + ((g*128 + n)*64 + o)*132 + cc] = acc;
    }
    for (int idx = threadIdx.x; idx < 64*3; idx += 256) {
        int o = idx / 3, cc = 129 + idx % 3;
        ws[OFF_WT + ((g*128 + n)*64 + o)*132 + cc] = 0.f;
    }
    if (threadIdx.x < D_) {
        int o = threadIdx.x;
        float acc = 0.f;
#pragma unroll
        for (int q = 0; q < QD_; ++q) acc += qn[q] * bb[q*D_ + o];
        ws[OFF_BEFF + (g*128 + n)*D_ + o] = acc;
    }
}

// VWP [h][cc][c pad132]; QKT [qk][h][ck][cc pad132]
__global__ void k_pack(const float* __restrict__ vW,
                       const float* __restrict__ qW,
                       const float* __restrict__ kW,
                       float* __restrict__ ws) {
    int stride = gridDim.x * blockDim.x;
    int t0 = blockIdx.x * blockDim.x + threadIdx.x;
    for (int idx = t0; idx < 2*C_*132; idx += stride) {
        int h = idx / (C_*132);
        int r = idx % (C_*132);
        int cc = r / 132, c = r % 132;
        ws[OFF_VWP + idx] = (c < C_) ? vW[(h*C_ + cc)*C_ + c] : 0.f;
    }
    for (int idx = t0; idx < 2*2*16*132; idx += stride) {
        int qk = idx / 4224;
        int r  = idx % 4224;
        int h  = r / 2112;
        int r2 = r % 2112;
        int ck = r2 / 132, cc = r2 % 132;
        const float* src = qk ? kW : qW;
        ws[OFF_QKT + idx] = (cc < C_) ? src[(h*C_ + cc)*CK_ + ck] : 0.f;
    }
}

// vto[b][n] = sum_t mask[b,t,n]
__global__ void k_vto(const float* __restrict__ mask, float* __restrict__ ws) {
    int idx = blockIdx.x * blockDim.x + threadIdx.x;  // 16*256 = 4096
    if (idx < B_*N_) {
        int b = idx >> 7, n = idx & 127;
        float acc = 0.f;
        for (int t = 0; t < T_; ++t) acc += mask[(b*T_ + t)*N_ + n];
        ws[OFF_VTO + idx] = acc;
    }
}

// ---------------- main recurrent kernel (cooperative) ----------------
// 256 blocks x 1024 threads (1 block/CU, 16 waves = 4/SIMD);
// block owns 2 batch elems x 8 nodes; h lives in comb[.][.][65..128].
__global__ void __launch_bounds__(1024, 4) k_main(
    const float* __restrict__ obs,
    const float* __restrict__ mask,
    const float* __restrict__ avg,
    const int* __restrict__ lengths,
    const float* __restrict__ qb,
    const float* __restrict__ kb,
    const float* __restrict__ vb,
    float* __restrict__ ws,
    float* __restrict__ out) {
    cg::grid_group grid = cg::this_grid();
    const int tid = threadIdx.x;
    const int blk = blockIdx.x;
    const int b0 = (blk >> 4) * 2;   // 16 batch-groups of 2
    const int n0 = (blk & 15) * 8;   // 16 node-groups of 8

    __shared__ __align__(16) float comb[2][8][132];    // [x65|h64|pad3=0], h persists across steps
    __shared__ __align__(16) float att2[2][2][8][132]; // [bi][h][il][c]
    __shared__ __align__(16) float qf[2][2][8][16];    // [bi][h][il][ck]
    __shared__ __align__(16) float s_l[32][129];
    __shared__ float maskL[2][128];
    __shared__ float rar_l[2][8];

    for (int i = tid; i < 2*8*132; i += 1024) ((float*)comb)[i] = 0.f;
    const int len0 = lengths[b0];
    const int len1 = lengths[b0 + 1];
    __syncthreads();

    const float4* VWP4 = (const float4*)(ws + OFF_VWP);
    const float4* QKT4 = (const float4*)(ws + OFF_QKT);
    const float4* KT4  = (const float4*)(ws + OFF_KT);
    float4*       VG4  = (float4*)(ws + OFF_VG);
    const float4* WT4  = (const float4*)(ws + OFF_WT);

    for (int t = 0; t < T_; ++t) {
        const int par = t & 1;
        // ---- A1: masks + rarity ----
        if (tid < 256) {
            int bi = tid >> 7, j = tid & 127;
            maskL[bi][j] = mask[((b0 + bi)*T_ + t)*N_ + j];
        } else if (tid < 272) {
            int t2 = tid - 256, bi = t2 >> 3, il = t2 & 7;
            int b = b0 + bi, n = n0 + il;
            float a = avg[(b*T_ + t)*N_ + n];
            rar_l[bi][il] = 0.5f * tanhf(a / (ws[OFF_VTO + b*N_ + n] + 1.f));
        }
        __syncthreads();
        // ---- A2: comb x-part (h-part already holds h from prev step) ----
        {
            int bi = tid >> 9, il = (tid >> 6) & 7, d = tid & 63;
            comb[bi][il][d] = obs[(((b0 + bi)*T_ + t)*N_ + n0 + il)*D_ + d];
            if (d == 0) comb[bi][il][64] = rar_l[bi][il];
        }
        __syncthreads();
        // ---- A3: q -> LDS, k -> global; float4 weight rows ----
        {
            int ck = tid & 15, il = (tid >> 4) & 7, h = (tid >> 7) & 1,
                bi = (tid >> 8) & 1, qk = tid >> 9;
            const float4* Wp = &QKT4[((qk*2 + h)*16 + ck)*33];
            const float4* cb = (const float4*)comb[bi][il];
            float4 a4 = {0.f, 0.f, 0.f, 0.f};
#pragma unroll 8
            for (int q4 = 0; q4 < 33; ++q4) {
                float4 w = Wp[q4], z = cb[q4];
                a4.x += w.x*z.x; a4.y += w.y*z.y; a4.z += w.z*z.z; a4.w += w.w*z.w;
            }
            float acc = a4.x + a4.y + a4.z + a4.w
                      + (qk ? kb[h*CK_ + ck] : qb[h*CK_ + ck]);
            if (!qk) qf[bi][h][il][ck] = acc;
            else ws[OFF_KT + (((par*B_ + b0 + bi)*H_ + h)*N_ + n0 + il)*CK_ + ck] = acc;
        }
        // ---- A4: v rows -> global (c4-contiguous wave fetches) ----
        for (int idx = tid; idx < 1056; idx += 1024) {
            int c4 = idx % 33, u = idx / 33;
            int il = u & 7, h = (u >> 3) & 1, bi = u >> 4;
            int c = c4 * 4;
            float4 acc;
            acc.x = (c + 0 < C_) ? vb[h*C_ + c + 0] : 0.f;
            acc.y = (c + 1 < C_) ? vb[h*C_ + c + 1] : 0.f;
            acc.z = (c + 2 < C_) ? vb[h*C_ + c + 2] : 0.f;
            acc.w = (c + 3 < C_) ? vb[h*C_ + c + 3] : 0.f;
            const float* cb2 = comb[bi][il];
#pragma unroll 8
            for (int cc = 0; cc < C_; ++cc) {
                float cm = cb2[cc];
                float4 wv = VWP4[(h*C_ + cc)*33 + c4];
                acc.x += cm*wv.x; acc.y += cm*wv.y; acc.z += cm*wv.z; acc.w += cm*wv.w;
            }
            VG4[(((par*B_ + b0 + bi)*H_ + h)*N_ + n0 + il)*33 + c4] = acc;
        }
        __threadfence();
        grid.sync();
        // ---- B1: scores ----
        {
            int j = tid & 127, h = (tid >> 7) & 1, g2 = tid >> 8;  // g2 0..3
#pragma unroll
            for (int bi = 0; bi < 2; ++bi) {
                const float4* kt = &KT4[(((par*B_ + b0 + bi)*H_ + h)*N_ + j)*4];
                float4 k0 = kt[0], k1 = kt[1], k2 = kt[2], k3 = kt[3];
                float mj = maskL[bi][j];
#pragma unroll
                for (int r = 0; r < 2; ++r) {
                    int il = g2*2 + r, ig = n0 + il, u = bi*16 + h*8 + il;
                    const float4* qp = (const float4*)qf[bi][h][il];
                    float4 q0 = qp[0], q1 = qp[1], q2 = qp[2], q3 = qp[3];
                    float acc = q0.x*k0.x + q0.y*k0.y + q0.z*k0.z + q0.w*k0.w
                              + q1.x*k1.x + q1.y*k1.y + q1.z*k1.z + q1.w*k1.w
                              + q2.x*k2.x + q2.y*k2.y + q2.z*k2.z + q2.w*k2.w
                              + q3.x*k3.x + q3.y*k3.y + q3.z*k3.z + q3.w*k3.w;
                    acc *= 0.25f;
                    acc = acc > 0.f ? acc : 0.2f*acc;
                    if (ig != j && (maskL[bi][ig] == 0.f || mj == 0.f)) acc = -9.0e15f;
                    s_l[u][j] = acc;
                }
            }
        }
        __syncthreads();
        // ---- B2: row softmax (16 waves x 2 rows) ----
        {
            int wave = tid >> 6, lane = tid & 63;
#pragma unroll
            for (int r = 0; r < 2; ++r) {
                int u = wave*2 + r;
                float x0 = s_l[u][lane], x1 = s_l[u][lane + 64];
                float m = fmaxf(x0, x1);
                for (int off = 32; off > 0; off >>= 1) m = fmaxf(m, __shfl_xor(m, off, 64));
                float e0 = __expf(x0 - m), e1 = __expf(x1 - m);
                float s = e0 + e1;
                for (int off = 32; off > 0; off >>= 1) s += __shfl_xor(s, off, 64);
                float inv = 1.f / s;
                s_l[u][lane] = e0*inv;
                s_l[u][lane + 64] = e1*inv;
            }
        }
        __syncthreads();
        // ---- B3: att2[bi][h] = P @ V (c4-contiguous) ----
        for (int idx = tid; idx < 1056; idx += 1024) {
            int c4 = idx % 33, u = idx / 33;
            int il = u & 7, h = (u >> 3) & 1, bi = u >> 4;
            const float* pr = s_l[bi*16 + h*8 + il];
            const float4* vg = &VG4[(((par*B_ + b0 + bi)*H_ + h)*N_)*33];
            float4 acc = {0.f, 0.f, 0.f, 0.f};
#pragma unroll 8
            for (int j = 0; j < N_; ++j) {
                float pp = pr[j];
                float4 v4 = vg[j*33 + c4];
                acc.x += pp*v4.x; acc.y += pp*v4.y; acc.z += pp*v4.z; acc.w += pp*v4.w;
            }
            ((float4*)att2[bi][h][il])[c4] = acc;
        }
        __syncthreads();
        // ---- C1: reset/update gates; h1 -> comb[65+o] ----
        int bi_c = tid >> 9, il_c = (tid >> 6) & 7, o = tid & 63;
        int n_c = n0 + il_c;
        float ug, h1;
        bool ob;
        {
            const float4* WR = &WT4[((0*128 + n_c)*64 + o)*33];
            const float4* WU = &WT4[((1*128 + n_c)*64 + o)*33];
            const float4* A0 = (const float4*)att2[bi_c][0][il_c];
            const float4* A1 = (const float4*)att2[bi_c][1][il_c];
            float accR = ws[OFF_BEFF + (0*128 + n_c)*D_ + o];
            float accU = ws[OFF_BEFF + (1*128 + n_c)*D_ + o];
#pragma unroll 8
            for (int q4 = 0; q4 < 33; ++q4) {
                float4 a0 = A0[q4], a1 = A1[q4];
                float4 wr = WR[q4], wu = WU[q4];
                float ax = 0.5f*(a0.x + a1.x), ay = 0.5f*(a0.y + a1.y);
                float az = 0.5f*(a0.z + a1.z), aw = 0.5f*(a0.w + a1.w);
                accR += ax*wr.x + ay*wr.y + az*wr.z + aw*wr.w;
                accU += ax*wu.x + ay*wu.y + az*wu.z + aw*wu.w;
            }
            float r = 1.f/(1.f + __expf(-accR));
            ug = 1.f/(1.f + __expf(-accU));
            ob = maskL[bi_c][n_c] > 0.f;
            float hcur = comb[bi_c][il_c][65 + o];   // own slot
            h1 = ob ? r*hcur : hcur;
            comb[bi_c][il_c][65 + o] = h1;           // own slot
        }
        __syncthreads();
        // ---- C2: candidate; h2; output ----
        {
            const float4* WC = &WT4[((2*128 + n_c)*64 + o)*33];
            const float4* CB = (const float4*)comb[bi_c][il_c];
            float accC = ws[OFF_BEFF + (2*128 + n_c)*D_ + o];
#pragma unroll 8
            for (int q4 = 0; q4 < 33; ++q4) {
                float4 z = CB[q4];
                float4 wc = WC[q4];
                accC += z.x*wc.x + z.y*wc.y + z.z*wc.z + z.w*wc.w;
            }
            float cand = tanhf(accC);
            float h2 = ob ? (1.f - ug)*h1 + ug*cand : h1;
            __syncthreads();                          // all comb reads done before h2 overwrite
            comb[bi_c][il_c][65 + o] = h2;
            int tf = (bi_c ? len1 : len0) - 1;
            if (t == tf) out[((b0 + bi_c)*N_ + n_c)*D_ + o] = h2;
        }
        __syncthreads();
    }
}

extern "C" void kernel_launch(void* const* d_in, const int* in_sizes, int n_in,
                              void* d_out, int out_size, void* d_ws, size_t ws_size,
                              hipStream_t stream) {
    (void)in_sizes; (void)n_in; (void)out_size; (void)ws_size;
    const float* obs   = (const float*)d_in[0];
    const float* mask  = (const float*)d_in[1];
    const float* avg   = (const float*)d_in[2];
    const float* plm   = (const float*)d_in[3];
    const int*   lens  = (const int*)d_in[4];
    // d_in[5] rarity_W: value-irrelevant (only zero-pattern of cur_adj is used)
    const float* pfW1  = (const float*)d_in[6];
    const float* pfb1  = (const float*)d_in[7];
    const float* pfW2  = (const float*)d_in[8];
    const float* pfb2  = (const float*)d_in[9];
    // d_in[10..13] pg_*: dead (adjacency values only tested ==0; softmax>0 always)
    const float* rstW  = (const float*)d_in[14];
    const float* rstb  = (const float*)d_in[15];
    const float* updW  = (const float*)d_in[16];
    const float* updb  = (const float*)d_in[17];
    const float* candW = (const float*)d_in[18];
    const float* candb = (const float*)d_in[19];
    const float* qW    = (const float*)d_in[20];
    const float* qb    = (const float*)d_in[21];
    const float* kW    = (const float*)d_in[22];
    const float* kb    = (const float*)d_in[23];
    const float* vW    = (const float*)d_in[24];
    const float* vb    = (const float*)d_in[25];
    float* ws  = (float*)d_ws;
    float* out = (float*)d_out;

    hipLaunchKernelGGL(k_qv,   dim3(128), dim3(128), 0, stream, plm, pfW1, pfb1, pfW2, pfb2, ws);
    hipLaunchKernelGGL(k_weff, dim3(384), dim3(256), 0, stream, rstW, updW, candW, rstb, updb, candb, ws);
    hipLaunchKernelGGL(k_pack, dim3(64),  dim3(256), 0, stream, vW, qW, kW, ws);
    hipLaunchKernelGGL(k_vto,  dim3(16),  dim3(256), 0, stream, mask, ws);

    void* args[] = {(void*)&obs, (void*)&mask, (void*)&avg, (void*)&lens,
                    (void*)&qb, (void*)&kb, (void*)&vb, (void*)&ws, (void*)&out};
    hipLaunchCooperativeKernel((void*)k_main, dim3(256), dim3(1024), args, 0, stream);
}

// Round 7
// 6791.126 us; speedup vs baseline: 2.1211x; 2.1211x over previous
//
#include <hip/hip_runtime.h>
#include <math.h>

#define B_   32
#define T_   64
#define N_   128
#define D_   64
#define C_   129
#define CK_  16
#define H_   2
#define QD_  5
#define PLM_ 768

// ---- workspace layout (float/uint slots) ----
constexpr int OFF_QV  = 0;                         // 640
constexpr int OFF_WB  = 640;                       // uint 3*128*65*64 bf16x2 gate weights [g][n][cc2][o]
constexpr int OFF_BE  = OFF_WB + 3*128*65*64;      // fp32 3*128*64
constexpr int OFF_VWB = OFF_BE + 3*128*64;         // uint 2*129*65  vW [h][c][c'2] bf16x2
constexpr int OFF_QKB = OFF_VWB + 2*129*65;        // uint 4*65*16   qkW [qk*2+h][cc2][ck] bf16x2 (packed over cc)
constexpr int OFF_VTO = OFF_QKB + 4*65*16;         // fp32 B*N
constexpr int OFF_H   = OFF_VTO + B_*N_;           // fp32 2*B*N*64 (double-buffered h exchange)
constexpr int OFF_CNT = OFF_H + 2*B_*N_*64;        // uint 32 barrier counters (memset to 0 each launch)

__device__ __forceinline__ float bl(unsigned w) { return __uint_as_float((w & 0xffffu) << 16); }
__device__ __forceinline__ float bh(unsigned w) { return __uint_as_float(w & 0xffff0000u); }
__device__ __forceinline__ unsigned short f2b(float f) {
    union { float f; unsigned u; } v; v.f = f;
    unsigned u = v.u;
    unsigned r = (u + 0x7fffu + ((u >> 16) & 1u)) >> 16;   // RNE; inputs finite
    return (unsigned short)r;
}
__device__ __forceinline__ float b2f(unsigned short s) {
    return __uint_as_float(((unsigned)s) << 16);
}

// ---------------- precompute kernels ----------------

__global__ void k_qv(const float* __restrict__ plm, const float* __restrict__ W1,
                     const float* __restrict__ b1, const float* __restrict__ W2,
                     const float* __restrict__ b2, float* __restrict__ ws) {
    int n = blockIdx.x, j = threadIdx.x;          // 128 x 128
    __shared__ float hid[128];
    float acc = b1[j];
    for (int p = 0; p < PLM_; ++p) acc += plm[n*PLM_ + p] * W1[p*128 + j];
    hid[j] = fmaxf(acc, 0.f);
    __syncthreads();
    if (j < QD_) {
        float a = b2[j];
        for (int q = 0; q < 128; ++q) a += hid[q] * W2[q*QD_ + j];
        ws[OFF_QV + n*QD_ + j] = a;
    }
}

// WB[g][n][cc2][o] = bf16x2( Weff[2cc2][o], Weff[2cc2+1][o] );  BE[g][n][o]
__global__ void k_weff(const float* __restrict__ rW, const float* __restrict__ uW,
                       const float* __restrict__ cW, const float* __restrict__ rb,
                       const float* __restrict__ ub, const float* __restrict__ cb,
                       float* __restrict__ ws) {
    int g = blockIdx.x >> 7, n = blockIdx.x & 127;   // 384 blocks x 256 thr
    const float* W  = (g == 0) ? rW : (g == 1) ? uW : cW;
    const float* bb = (g == 0) ? rb : (g == 1) ? ub : cb;
    float qn[QD_];
#pragma unroll
    for (int q = 0; q < QD_; ++q) qn[q] = ws[OFF_QV + n*QD_ + q];
    unsigned* WB = (unsigned*)ws + OFF_WB;
    for (int idx = threadIdx.x; idx < 65*64; idx += 256) {
        int c2 = idx >> 6, o = idx & 63;
        float w0 = 0.f, w1 = 0.f;
#pragma unroll
        for (int q = 0; q < QD_; ++q) w0 += qn[q] * W[(q*C_ + 2*c2)*D_ + o];
        if (2*c2 + 1 < C_) {
#pragma unroll
            for (int q = 0; q < QD_; ++q) w1 += qn[q] * W[(q*C_ + 2*c2 + 1)*D_ + o];
        }
        WB[((g*128 + n)*65 + c2)*64 + o] = (unsigned)f2b(w0) | ((unsigned)f2b(w1) << 16);
    }
    if (threadIdx.x < D_) {
        int o = threadIdx.x;
        float acc = 0.f;
#pragma unroll
        for (int q = 0; q < QD_; ++q) acc += qn[q] * bb[q*D_ + o];
        ws[OFF_BE + (g*128 + n)*D_ + o] = acc;
    }
}

// VWB [h][c][c'2]; QKB [(qk*2+h)][cc2][ck]
__global__ void k_pack(const float* __restrict__ vW, const float* __restrict__ qW,
                       const float* __restrict__ kW, float* __restrict__ ws) {
    int stride = gridDim.x * blockDim.x;
    int t0 = blockIdx.x * blockDim.x + threadIdx.x;
    unsigned* VWB = (unsigned*)ws + OFF_VWB;
    unsigned* QKB = (unsigned*)ws + OFF_QKB;
    for (int idx = t0; idx < 2*C_*65; idx += stride) {
        int h = idx / (C_*65), r = idx % (C_*65);
        int c = r / 65, c2 = r % 65;
        float w0 = vW[(h*C_ + c)*C_ + 2*c2];
        float w1 = (2*c2 + 1 < C_) ? vW[(h*C_ + c)*C_ + 2*c2 + 1] : 0.f;
        VWB[idx] = (unsigned)f2b(w0) | ((unsigned)f2b(w1) << 16);
    }
    for (int idx = t0; idx < 4*65*16; idx += stride) {
        int g = idx / (65*16), r = idx % (65*16);
        int qk = g >> 1, h = g & 1;
        int c2 = r / 16, ck = r % 16;
        const float* src = qk ? kW : qW;
        float w0 = src[(h*C_ + 2*c2)*CK_ + ck];
        float w1 = (2*c2 + 1 < C_) ? src[(h*C_ + 2*c2 + 1)*CK_ + ck] : 0.f;
        QKB[idx] = (unsigned)f2b(w0) | ((unsigned)f2b(w1) << 16);
    }
}

__global__ void k_vto(const float* __restrict__ mask, float* __restrict__ ws) {
    int idx = blockIdx.x * blockDim.x + threadIdx.x;
    if (idx < B_*N_) {
        int b = idx >> 7, n = idx & 127;
        float acc = 0.f;
        for (int t = 0; t < T_; ++t) acc += mask[(b*T_ + t)*N_ + n];
        ws[OFF_VTO + idx] = acc;
    }
}

// ---------------- main recurrent kernel ----------------
// 256 blocks x 512 threads, cooperative (co-residency only, NO grid.sync).
// block = (b = blk>>3, node-group ng = blk&7 : 16 nodes). Only h is exchanged
// cross-block, via relaxed agent-scope atomics + per-batch 8-block barrier.
__global__ void __launch_bounds__(512, 2) k_main(
    const float* __restrict__ obs, const float* __restrict__ mask,
    const float* __restrict__ avg, const int* __restrict__ lengths,
    const float* __restrict__ qb, const float* __restrict__ kb,
    const float* __restrict__ vb, float* __restrict__ ws,
    float* __restrict__ out) {
    const int tid = threadIdx.x;
    const int b  = blockIdx.x >> 3;
    const int ng = blockIdx.x & 7;
    const int n0 = ng * 16;

    __shared__ unsigned short comball[130][130]; // [c][j] bf16: c<64 obs, 64 rar, 65+d h, 129 zero
    __shared__ unsigned short sP[32][130];       // scores -> P (bf16, in place)
    __shared__ unsigned short kz[2][16][130];    // kall [2][128][16] (u16 view) then zb [h][i][c]
    __shared__ float atth[16][130];              // att fp32 -> [i][0..63] becomes h1
    __shared__ float qfv[2][16][16];
    __shared__ float h_own[16][64];
    __shared__ float maskL[128];

    const unsigned* WB  = (const unsigned*)ws + OFF_WB;
    const unsigned* VWB = (const unsigned*)ws + OFF_VWB;
    const unsigned* QKB = (const unsigned*)ws + OFF_QKB;
    float* Hx = ws + OFF_H;
    unsigned* CNT = (unsigned*)ws + OFF_CNT;
    unsigned short* kallU = (unsigned short*)kz;   // [ (h*128+j)*16 + ck ]
    unsigned short* zbU   = (unsigned short*)kz;   // [ (h*16+i)*130 + c ]

    for (int i = tid; i < 16*64; i += 512) h_own[i >> 6][i & 63] = 0.f;
    if (tid < 130) comball[129][tid] = 0;
    const int lenb = lengths[b];
    __syncthreads();

    for (int t = 0; t < T_; ++t) {
        // ---- P0: barrier + import h (all 128 nodes) ----
        if (t > 0) {
            if (tid == 0) {
                unsigned target = 8u * (unsigned)t;
                while (__hip_atomic_load(&CNT[b], __ATOMIC_RELAXED,
                                         __HIP_MEMORY_SCOPE_AGENT) < target)
                    __builtin_amdgcn_s_sleep(8);
            }
            __syncthreads();
            const float* Hr = Hx + ((size_t)((t & 1)*B_ + b)*N_)*64;
            for (int idx = tid; idx < 128*64; idx += 512) {
                int j = idx >> 6, d = idx & 63;
                float hv;
                if ((j >> 4) == ng) hv = h_own[j & 15][d];
                else hv = __hip_atomic_load(Hr + idx, __ATOMIC_RELAXED,
                                            __HIP_MEMORY_SCOPE_AGENT);
                comball[65 + d][j] = f2b(hv);
            }
        } else {
            for (int idx = tid; idx < 128*64; idx += 512)
                comball[65 + (idx & 63)][idx >> 6] = 0;
        }
        // ---- P1: x-part for all nodes ----
        {
            const float* obsR = obs + ((size_t)(b*T_ + t)*N_)*D_;
            for (int idx = tid; idx < 128*64; idx += 512)
                comball[idx & 63][idx >> 6] = f2b(obsR[idx]);
            if (tid < 128) {
                int j = tid;
                maskL[j] = mask[(b*T_ + t)*N_ + j];
                float a = avg[(b*T_ + t)*N_ + j];
                comball[64][j] = f2b(0.5f * tanhf(a / (ws[OFF_VTO + b*N_ + j] + 1.f)));
            }
        }
        __syncthreads();
        // ---- P2: q for own 16 nodes ----
        {
            int ck = tid & 15, i = (tid >> 4) & 15, h = tid >> 8;
            int jj = n0 + i;
            float acc = qb[h*CK_ + ck];
            const unsigned* Wq = QKB + (h*65)*16 + ck;
#pragma unroll 13
            for (int c2 = 0; c2 < 65; ++c2) {
                unsigned w = Wq[c2*16];
                acc += bl(w)*b2f(comball[2*c2][jj]) + bh(w)*b2f(comball[2*c2+1][jj]);
            }
            qfv[h][i][ck] = acc;
        }
        // ---- P3: k for ALL 128 nodes (recomputed locally; no exchange) ----
        {
            int ck = tid & 15, jg = (tid >> 4) & 15, h = tid >> 8;
            float acc[8];
            float kbias = kb[h*CK_ + ck];
#pragma unroll
            for (int jq = 0; jq < 8; ++jq) acc[jq] = kbias;
            const unsigned* Wk = QKB + ((2 + h)*65)*16 + ck;
            for (int c2 = 0; c2 < 65; ++c2) {
                unsigned w = Wk[c2*16];
                float w0 = bl(w), w1 = bh(w);
#pragma unroll
                for (int jq = 0; jq < 8; ++jq) {
                    int j = jg*8 + jq;
                    acc[jq] += w0*b2f(comball[2*c2][j]) + w1*b2f(comball[2*c2+1][j]);
                }
            }
#pragma unroll
            for (int jq = 0; jq < 8; ++jq)
                kallU[(h*128 + jg*8 + jq)*16 + ck] = f2b(acc[jq]);
        }
        __syncthreads();
        // ---- P4: scores (bf16) ----
        {
            int j = tid & 127, iq = (tid >> 7) & 1, h = tid >> 8;
            float kj[16];
#pragma unroll
            for (int ck = 0; ck < 16; ++ck) kj[ck] = b2f(kallU[(h*128 + j)*16 + ck]);
            float mj = maskL[j];
#pragma unroll
            for (int i8 = 0; i8 < 8; ++i8) {
                int il = iq*8 + i8, ig = n0 + il;
                float acc = 0.f;
#pragma unroll
                for (int ck = 0; ck < 16; ++ck) acc += qfv[h][il][ck]*kj[ck];
                acc *= 0.25f;
                acc = acc > 0.f ? acc : 0.2f*acc;
                if (ig != j && (maskL[ig] == 0.f || mj == 0.f)) acc = -9.0e15f;
                sP[h*16 + il][j] = f2b(acc);
            }
        }
        __syncthreads();
        // ---- P5: softmax (in place, P bf16) ----
        {
            int wave = tid >> 6, lane = tid & 63;
#pragma unroll
            for (int r = 0; r < 4; ++r) {
                int u = wave*4 + r;
                float x0 = b2f(sP[u][lane]), x1 = b2f(sP[u][lane + 64]);
                float m = fmaxf(x0, x1);
                for (int off = 32; off > 0; off >>= 1) m = fmaxf(m, __shfl_xor(m, off, 64));
                float e0 = __expf(x0 - m), e1 = __expf(x1 - m);
                float s = e0 + e1;
                for (int off = 32; off > 0; off >>= 1) s += __shfl_xor(s, off, 64);
                float inv = 1.f / s;
                sP[u][lane] = f2b(e0*inv);
                sP[u][lane + 64] = f2b(e1*inv);
            }
        }
        __syncthreads();
        // ---- P6: z[h][i][c] = sum_j P[i][j]*comb[j][c]  (reuses kz region) ----
        {
            int cs = tid & 15, i = (tid >> 4) & 15, h = tid >> 8;
            float acc[9];
#pragma unroll
            for (int m = 0; m < 9; ++m) acc[m] = 0.f;
            const unsigned short* Pr = sP[h*16 + i];
            for (int j = 0; j < 128; ++j) {
                float p = b2f(Pr[j]);
#pragma unroll
                for (int m = 0; m < 9; ++m) {
                    int c = cs + 16*m;
                    if (c < 129) acc[m] += p * b2f(comball[c][j]);
                }
            }
#pragma unroll
            for (int m = 0; m < 9; ++m) {
                int c = cs + 16*m;
                if (c < 129) zbU[(h*16 + i)*130 + c] = f2b(acc[m]);
            }
        }
        __syncthreads();
        // ---- P7: att[i][c'] = 0.5*( sum_h vW_h^T z_h + vb0 + vb1 ) ----
        {
            int i = tid >> 5, w = tid & 31;
            float a0x = 0.f, a0y = 0.f, a1x = 0.f, a1y = 0.f, a2x = 0.f;
#pragma unroll
            for (int h = 0; h < 2; ++h) {
                const unsigned* Vh = VWB + (h*C_)*65;
                const unsigned short* Zr = zbU + (h*16 + i)*130;
                for (int c = 0; c < 129; ++c) {
                    float zv = b2f(Zr[c]);
                    unsigned wA = Vh[c*65 + w];
                    unsigned wB = Vh[c*65 + w + 32];
                    a0x += zv*bl(wA); a0y += zv*bh(wA);
                    a1x += zv*bl(wB); a1y += zv*bh(wB);
                    if (w == 0) a2x += zv*bl(Vh[c*65 + 64]);
                }
            }
            int cA = 2*w, cB = 2*(w + 32);
            atth[i][cA]     = 0.5f*(a0x + vb[cA]     + vb[C_ + cA]);
            atth[i][cA + 1] = 0.5f*(a0y + vb[cA + 1] + vb[C_ + cA + 1]);
            atth[i][cB]     = 0.5f*(a1x + vb[cB]     + vb[C_ + cB]);
            atth[i][cB + 1] = 0.5f*(a1y + vb[cB + 1] + vb[C_ + cB + 1]);
            if (w == 0) {
                atth[i][128] = 0.5f*(a2x + vb[128] + vb[C_ + 128]);
                atth[i][129] = 0.f;
            }
        }
        __syncthreads();
        // ---- P8: R,U gates; h1 ----
        int il = tid >> 5, o = (tid & 31)*2, n = n0 + il;
        float ugx, ugy, h1x, h1y;
        bool ob;
        {
            const unsigned* WR = WB + ((0*128 + n)*65)*64 + o;
            const unsigned* WU = WB + ((1*128 + n)*65)*64 + o;
            float rx = ws[OFF_BE + (0*128 + n)*64 + o];
            float ry = ws[OFF_BE + (0*128 + n)*64 + o + 1];
            float ux = ws[OFF_BE + (1*128 + n)*64 + o];
            float uy = ws[OFF_BE + (1*128 + n)*64 + o + 1];
#pragma unroll 5
            for (int c2 = 0; c2 < 65; ++c2) {
                float a0 = atth[il][2*c2], a1 = atth[il][2*c2 + 1];
                unsigned r0 = WR[c2*64], r1 = WR[c2*64 + 1];
                unsigned u0 = WU[c2*64], u1 = WU[c2*64 + 1];
                rx += a0*bl(r0) + a1*bh(r0);
                ry += a0*bl(r1) + a1*bh(r1);
                ux += a0*bl(u0) + a1*bh(u0);
                uy += a0*bl(u1) + a1*bh(u1);
            }
            float rgx = 1.f/(1.f + __expf(-rx)), rgy = 1.f/(1.f + __expf(-ry));
            ugx = 1.f/(1.f + __expf(-ux));  ugy = 1.f/(1.f + __expf(-uy));
            ob = maskL[n] > 0.f;
            float h0x = h_own[il][o], h0y = h_own[il][o + 1];
            h1x = ob ? rgx*h0x : h0x;
            h1y = ob ? rgy*h0y : h0y;
        }
        __syncthreads();                 // all att reads done
        atth[il][o] = h1x;               // overlay h1 into atth[.][0..63]
        atth[il][o + 1] = h1y;
        __syncthreads();
        // ---- P9: candidate; h2; export ----
        {
            const unsigned* WC = WB + ((2*128 + n)*65)*64 + o;
            float cx = ws[OFF_BE + (2*128 + n)*64 + o];
            float cy = ws[OFF_BE + (2*128 + n)*64 + o + 1];
            int jj = n0 + il;
#pragma unroll 5
            for (int c2 = 0; c2 < 65; ++c2) {
                int cc = 2*c2;
                float z0 = (cc < 65) ? b2f(comball[cc][jj])
                         : atth[il][cc - 65];
                float z1 = (cc + 1 < 65) ? b2f(comball[cc + 1][jj])
                         : ((cc + 1 < 129) ? atth[il][cc - 64] : 0.f);
                unsigned c0 = WC[c2*64], c1 = WC[c2*64 + 1];
                cx += z0*bl(c0) + z1*bh(c0);
                cy += z0*bl(c1) + z1*bh(c1);
            }
            float candx = tanhf(cx), candy = tanhf(cy);
            float h2x = ob ? (1.f - ugx)*h1x + ugx*candx : h1x;
            float h2y = ob ? (1.f - ugy)*h1y + ugy*candy : h1y;
            h_own[il][o] = h2x;
            h_own[il][o + 1] = h2y;
            if (t == lenb - 1) {
                out[((size_t)(b*N_ + n))*D_ + o]     = h2x;
                out[((size_t)(b*N_ + n))*D_ + o + 1] = h2y;
            }
            if (t < T_ - 1) {
                float* Hw = Hx + ((size_t)(((t + 1) & 1)*B_ + b)*N_ + n)*64;
                __hip_atomic_store(Hw + o,     h2x, __ATOMIC_RELAXED, __HIP_MEMORY_SCOPE_AGENT);
                __hip_atomic_store(Hw + o + 1, h2y, __ATOMIC_RELAXED, __HIP_MEMORY_SCOPE_AGENT);
            }
        }
        __syncthreads();                 // drains all threads' stores (waitcnt before barrier)
        if (t < T_ - 1 && tid == 0)
            __hip_atomic_fetch_add(&CNT[b], 1u, __ATOMIC_RELAXED, __HIP_MEMORY_SCOPE_AGENT);
    }
}

extern "C" void kernel_launch(void* const* d_in, const int* in_sizes, int n_in,
                              void* d_out, int out_size, void* d_ws, size_t ws_size,
                              hipStream_t stream) {
    (void)in_sizes; (void)n_in; (void)out_size; (void)ws_size;
    const float* obs   = (const float*)d_in[0];
    const float* mask  = (const float*)d_in[1];
    const float* avg   = (const float*)d_in[2];
    const float* plm   = (const float*)d_in[3];
    const int*   lens  = (const int*)d_in[4];
    // d_in[5] rarity_W: only the ==0 pattern of cur_adj matters -> dead values
    const float* pfW1  = (const float*)d_in[6];
    const float* pfb1  = (const float*)d_in[7];
    const float* pfW2  = (const float*)d_in[8];
    const float* pfb2  = (const float*)d_in[9];
    // d_in[10..13] pg_*: dead (softmax adjacency > 0 always)
    const float* rstW  = (const float*)d_in[14];
    const float* rstb  = (const float*)d_in[15];
    const float* updW  = (const float*)d_in[16];
    const float* updb  = (const float*)d_in[17];
    const float* candW = (const float*)d_in[18];
    const float* candb = (const float*)d_in[19];
    const float* qW    = (const float*)d_in[20];
    const float* qb    = (const float*)d_in[21];
    const float* kW    = (const float*)d_in[22];
    const float* kb    = (const float*)d_in[23];
    const float* vW    = (const float*)d_in[24];
    const float* vb    = (const float*)d_in[25];
    float* ws  = (float*)d_ws;
    float* out = (float*)d_out;

    hipMemsetAsync((char*)d_ws + (size_t)OFF_CNT*4, 0, 32*sizeof(unsigned), stream);
    hipLaunchKernelGGL(k_qv,   dim3(128), dim3(128), 0, stream, plm, pfW1, pfb1, pfW2, pfb2, ws);
    hipLaunchKernelGGL(k_weff, dim3(384), dim3(256), 0, stream, rstW, updW, candW, rstb, updb, candb, ws);
    hipLaunchKernelGGL(k_pack, dim3(64),  dim3(256), 0, stream, vW, qW, kW, ws);
    hipLaunchKernelGGL(k_vto,  dim3(16),  dim3(256), 0, stream, mask, ws);

    void* args[] = {(void*)&obs, (void*)&mask, (void*)&avg, (void*)&lens,
                    (void*)&qb, (void*)&kb, (void*)&vb, (void*)&ws, (void*)&out};
    hipLaunchCooperativeKernel((void*)k_main, dim3(256), dim3(512), args, 0, stream);
}

// Round 8
// 3707.329 us; speedup vs baseline: 3.8854x; 1.8318x over previous
//
#include <hip/hip_runtime.h>
#include <math.h>

#define B_   32
#define T_   64
#define N_   128
#define D_   64
#define C_   129
#define CK_  16
#define H_   2
#define QD_  5
#define PLM_ 768

typedef _Float16 h2v __attribute__((ext_vector_type(2)));
typedef _Float16 h4v __attribute__((ext_vector_type(4)));

// ---- workspace layout (float/u32 slots) ----
constexpr int OFF_QV   = 0;                           // 640
constexpr int OFF_BE   = 640;                         // fp32 3*128*64
constexpr int OFF_WB2  = OFF_BE + 3*128*64;           // h2v 3*128*65*64 gate weights [g][n][c2][o], pair over c'
constexpr int OFF_VWB2 = OFF_WB2 + 3*128*65*64;       // h2v 2*65*132   vW [h][c2][c'], pair over z-c
constexpr int OFF_QKB2 = OFF_VWB2 + 2*65*132;         // h2v 4*65*16    qkW [qk*2+h][c2][ck], pair over comb-c
constexpr int OFF_ATTB = OFF_QKB2 + 4*65*16;          // fp32 132: 0.5*(vb0+vb1)
constexpr int OFF_VTO  = OFF_ATTB + 132;              // fp32 B*N
constexpr int OFF_H    = OFF_VTO + B_*N_;             // fp32 2*B*N*64 double-buffered h exchange
constexpr int OFF_CNT  = OFF_H + 2*B_*N_*64;          // u32 x32 barrier counters (memset 0 per launch)

#if __has_builtin(__builtin_amdgcn_fdot2)
__device__ __forceinline__ float fdot2(h2v a, h2v b, float c) {
    return __builtin_amdgcn_fdot2(a, b, c, false);
}
#else
__device__ __forceinline__ float fdot2(h2v a, h2v b, float c) {
    return c + (float)a.x*(float)b.x + (float)a.y*(float)b.y;
}
#endif

// ---------------- precompute kernels ----------------

__global__ void k_qv(const float* __restrict__ plm, const float* __restrict__ W1,
                     const float* __restrict__ b1, const float* __restrict__ W2,
                     const float* __restrict__ b2, float* __restrict__ ws) {
    int n = blockIdx.x, j = threadIdx.x;          // 128 x 128
    __shared__ float hid[128];
    float acc = b1[j];
    for (int p = 0; p < PLM_; ++p) acc += plm[n*PLM_ + p] * W1[p*128 + j];
    hid[j] = fmaxf(acc, 0.f);
    __syncthreads();
    if (j < QD_) {
        float a = b2[j];
        for (int q = 0; q < 128; ++q) a += hid[q] * W2[q*QD_ + j];
        ws[OFF_QV + n*QD_ + j] = a;
    }
}

// WB2[g][n][c2][o] = h2v( Weff[c'=2c2][o], Weff[2c2+1][o] );  BE[g][n][o]
__global__ void k_weff(const float* __restrict__ rW, const float* __restrict__ uW,
                       const float* __restrict__ cW, const float* __restrict__ rb,
                       const float* __restrict__ ub, const float* __restrict__ cb,
                       float* __restrict__ ws) {
    int g = blockIdx.x >> 7, n = blockIdx.x & 127;   // 384 blocks x 256 thr
    const float* W  = (g == 0) ? rW : (g == 1) ? uW : cW;
    const float* bb = (g == 0) ? rb : (g == 1) ? ub : cb;
    float qn[QD_];
#pragma unroll
    for (int q = 0; q < QD_; ++q) qn[q] = ws[OFF_QV + n*QD_ + q];
    h2v* WB = (h2v*)(ws + OFF_WB2);
    for (int idx = threadIdx.x; idx < 65*64; idx += 256) {
        int c2 = idx >> 6, o = idx & 63;
        float w0 = 0.f, w1 = 0.f;
#pragma unroll
        for (int q = 0; q < QD_; ++q) w0 += qn[q] * W[(q*C_ + 2*c2)*D_ + o];
        if (2*c2 + 1 < C_) {
#pragma unroll
            for (int q = 0; q < QD_; ++q) w1 += qn[q] * W[(q*C_ + 2*c2 + 1)*D_ + o];
        }
        WB[((g*128 + n)*65 + c2)*64 + o] = h2v{(_Float16)w0, (_Float16)w1};
    }
    if (threadIdx.x < D_) {
        int o = threadIdx.x;
        float acc = 0.f;
#pragma unroll
        for (int q = 0; q < QD_; ++q) acc += qn[q] * bb[q*D_ + o];
        ws[OFF_BE + (g*128 + n)*D_ + o] = acc;
    }
}

// VWB2[h][c2][c'] (pair over z-c); QKB2[qk*2+h][c2][ck] (pair over comb-c); ATTB
__global__ void k_pack(const float* __restrict__ vW, const float* __restrict__ qW,
                       const float* __restrict__ kW, const float* __restrict__ vb,
                       float* __restrict__ ws) {
    int stride = gridDim.x * blockDim.x;
    int t0 = blockIdx.x * blockDim.x + threadIdx.x;
    h2v* VWB = (h2v*)(ws + OFF_VWB2);
    h2v* QKB = (h2v*)(ws + OFF_QKB2);
    for (int idx = t0; idx < 2*65*132; idx += stride) {
        int h = idx / (65*132), r = idx % (65*132);
        int c2 = r / 132, cp = r % 132;
        float w0 = (cp < C_) ? vW[(h*C_ + 2*c2)*C_ + cp] : 0.f;
        float w1 = (cp < C_ && 2*c2 + 1 < C_) ? vW[(h*C_ + 2*c2 + 1)*C_ + cp] : 0.f;
        VWB[idx] = h2v{(_Float16)w0, (_Float16)w1};
    }
    for (int idx = t0; idx < 4*65*16; idx += stride) {
        int g = idx / (65*16), r = idx % (65*16);
        int qk = g >> 1, h = g & 1;
        int c2 = r / 16, ck = r % 16;
        const float* src = qk ? kW : qW;
        float w0 = src[(h*C_ + 2*c2)*CK_ + ck];
        float w1 = (2*c2 + 1 < C_) ? src[(h*C_ + 2*c2 + 1)*CK_ + ck] : 0.f;
        QKB[idx] = h2v{(_Float16)w0, (_Float16)w1};
    }
    for (int idx = t0; idx < 132; idx += stride)
        ws[OFF_ATTB + idx] = (idx < C_) ? 0.5f*(vb[idx] + vb[C_ + idx]) : 0.f;
}

__global__ void k_vto(const float* __restrict__ mask, float* __restrict__ ws) {
    int idx = blockIdx.x * blockDim.x + threadIdx.x;
    if (idx < B_*N_) {
        int b = idx >> 7, n = idx & 127;
        float acc = 0.f;
        for (int t = 0; t < T_; ++t) acc += mask[(b*T_ + t)*N_ + n];
        ws[OFF_VTO + idx] = acc;
    }
}

// ---------------- main recurrent kernel ----------------
// 256 blocks x 1024 threads, cooperative (co-residency only, NO grid.sync).
// block = (b = blk>>3, ng = blk&7 : 16 nodes). Only h crosses blocks
// (relaxed agent-scope atomics + per-batch 8-block counter barrier).
__global__ void __launch_bounds__(1024, 4) k_main(
    const float* __restrict__ obs, const float* __restrict__ mask,
    const float* __restrict__ avg, const int* __restrict__ lengths,
    const float* __restrict__ qb, const float* __restrict__ kb,
    float* __restrict__ ws, float* __restrict__ out) {
    const int tid = threadIdx.x;
    const int b  = blockIdx.x >> 3;
    const int ng = blockIdx.x & 7;
    const int n0 = ng * 16;

    // LDS: 33792 + 8448 + 10368 + 512 + 4096 = 57216 B  (< 64 KB runtime cap)
    __shared__ __align__(16) _Float16 comball[128*132]; // [j][c]: 0..63 obs,64 rar,65..128 h,129..131 pad0
    __shared__ __align__(16) char regA[8448];  // sP f16[32][132] -> { atthh h2v[16*66] @0 | h1L f32[16*66] @4224 } -> candin @0
    __shared__ __align__(16) char regB[10368]; // kall f16[2*128*18] @0 + qf f16[2*16*18] @9216 -> zb h2v[2*16*66] @0
    __shared__ float maskL[128];
    __shared__ float h_own[16*64];

    _Float16* sPH    = (_Float16*)regA;
    h2v*      atthh  = (h2v*)regA;
    float*    h1L    = (float*)(regA + 4224);
    h2v*      candin = (h2v*)regA;
    _Float16* kall   = (_Float16*)regB;
    _Float16* qfH    = (_Float16*)(regB + 9216);
    h2v*      zb     = (h2v*)regB;

    float* Hx = ws + OFF_H;
    unsigned* CNT = (unsigned*)(ws + OFF_CNT);
    const h2v* QKB = (const h2v*)(ws + OFF_QKB2);
    const h2v* WB  = (const h2v*)(ws + OFF_WB2);

    for (int i = tid; i < 16*64; i += 1024) h_own[i] = 0.f;
    if (tid < 384) comball[(tid/3)*132 + 129 + tid%3] = (_Float16)0.f;
    const int lenb = lengths[b];
    __syncthreads();

    for (int t = 0; t < T_; ++t) {
        // ---- P0: barrier + import h ----
        if (t > 0) {
            if (tid == 0) {
                unsigned target = 8u * (unsigned)t;
                while (__hip_atomic_load(&CNT[b], __ATOMIC_RELAXED,
                                         __HIP_MEMORY_SCOPE_AGENT) < target)
                    __builtin_amdgcn_s_sleep(2);
            }
            __syncthreads();
            const float* Hr = Hx + (size_t)((t & 1)*B_ + b)*N_*64;
#pragma unroll
            for (int p = 0; p < 8; ++p) {
                int idx = tid + p*1024;
                int j = idx >> 6, d = idx & 63;
                float hv = ((j >> 4) == ng) ? h_own[(j & 15)*64 + d]
                         : __hip_atomic_load((float*)Hr + idx, __ATOMIC_RELAXED,
                                             __HIP_MEMORY_SCOPE_AGENT);
                comball[j*132 + 65 + d] = (_Float16)hv;
            }
        } else {
#pragma unroll
            for (int p = 0; p < 8; ++p) {
                int idx = tid + p*1024;
                comball[(idx >> 6)*132 + 65 + (idx & 63)] = (_Float16)0.f;
            }
        }
        // ---- P1: x-part ----
        {
            const float* obsR = obs + (size_t)(b*T_ + t)*N_*D_;
#pragma unroll
            for (int p = 0; p < 8; ++p) {
                int idx = tid + p*1024;
                comball[(idx >> 6)*132 + (idx & 63)] = (_Float16)obsR[idx];
            }
            if (tid < 128) {
                maskL[tid] = mask[(b*T_ + t)*N_ + tid];
                float a = avg[(b*T_ + t)*N_ + tid];
                comball[tid*132 + 64] =
                    (_Float16)(0.5f * tanhf(a / (ws[OFF_VTO + b*N_ + tid] + 1.f)));
            }
        }
        __syncthreads();
        // ---- P2: q for own 16 nodes (512 threads) ----
        if (tid < 512) {
            int ck = tid & 15, i = (tid >> 4) & 15, h = tid >> 8;
            const h2v* Wq = QKB + (h*65)*16 + ck;
            const h2v* cbj = (const h2v*)(comball + (n0 + i)*132);
            float acc = qb[h*CK_ + ck];
#pragma unroll 13
            for (int c2 = 0; c2 < 65; ++c2) acc = fdot2(cbj[c2], Wq[c2*16], acc);
            qfH[(h*16 + i)*18 + ck] = (_Float16)acc;
        }
        // ---- P3: k for ALL 128 nodes (4 j per thread) ----
        {
            int ck = tid & 15, jg = (tid >> 4) & 31, h = tid >> 9;
            const h2v* Wk = QKB + ((2 + h)*65)*16 + ck;
            const h2v* c0p = (const h2v*)(comball + (jg*4 + 0)*132);
            const h2v* c1p = (const h2v*)(comball + (jg*4 + 1)*132);
            const h2v* c2p = (const h2v*)(comball + (jg*4 + 2)*132);
            const h2v* c3p = (const h2v*)(comball + (jg*4 + 3)*132);
            float kbv = kb[h*CK_ + ck];
            float a0 = kbv, a1 = kbv, a2 = kbv, a3 = kbv;
#pragma unroll 5
            for (int c2 = 0; c2 < 65; ++c2) {
                h2v w = Wk[c2*16];
                a0 = fdot2(c0p[c2], w, a0);
                a1 = fdot2(c1p[c2], w, a1);
                a2 = fdot2(c2p[c2], w, a2);
                a3 = fdot2(c3p[c2], w, a3);
            }
            kall[(h*128 + jg*4 + 0)*18 + ck] = (_Float16)a0;
            kall[(h*128 + jg*4 + 1)*18 + ck] = (_Float16)a1;
            kall[(h*128 + jg*4 + 2)*18 + ck] = (_Float16)a2;
            kall[(h*128 + jg*4 + 3)*18 + ck] = (_Float16)a3;
        }
        __syncthreads();
        // ---- P4: scores ----
        {
            int j = tid & 127, q4 = (tid >> 7) & 3, h = tid >> 9;
            const h2v* kp = (const h2v*)(kall + (h*128 + j)*18);
            h2v k0 = kp[0], k1 = kp[1], k2 = kp[2], k3 = kp[3],
                k4 = kp[4], k5 = kp[5], k6 = kp[6], k7 = kp[7];
            float mj = maskL[j];
#pragma unroll
            for (int ii = 0; ii < 4; ++ii) {
                int i = q4*4 + ii, ig = n0 + i;
                const h2v* qp = (const h2v*)(qfH + (h*16 + i)*18);
                float acc = 0.f;
                acc = fdot2(qp[0], k0, acc); acc = fdot2(qp[1], k1, acc);
                acc = fdot2(qp[2], k2, acc); acc = fdot2(qp[3], k3, acc);
                acc = fdot2(qp[4], k4, acc); acc = fdot2(qp[5], k5, acc);
                acc = fdot2(qp[6], k6, acc); acc = fdot2(qp[7], k7, acc);
                acc *= 0.25f;
                acc = acc > 0.f ? acc : 0.2f*acc;
                if (ig != j && (maskL[ig] == 0.f || mj == 0.f)) acc = -60000.f;
                sPH[(h*16 + i)*132 + j] = (_Float16)acc;
            }
        }
        __syncthreads();
        // ---- P5: softmax (16 waves x 2 rows) ----
        {
            int wave = tid >> 6, lane = tid & 63;
#pragma unroll
            for (int r = 0; r < 2; ++r) {
                int u = wave*2 + r;
                float x0 = (float)sPH[u*132 + lane], x1 = (float)sPH[u*132 + lane + 64];
                float m = fmaxf(x0, x1);
                for (int off = 32; off > 0; off >>= 1) m = fmaxf(m, __shfl_xor(m, off, 64));
                float e0 = __expf(x0 - m), e1 = __expf(x1 - m);
                float s = e0 + e1;
                for (int off = 32; off > 0; off >>= 1) s += __shfl_xor(s, off, 64);
                float inv = 1.f / s;
                sPH[u*132 + lane] = (_Float16)(e0*inv);
                sPH[u*132 + lane + 64] = (_Float16)(e1*inv);
            }
        }
        __syncthreads();
        // ---- P6: z[h][i][cw] = sum_j P[i][j]*comb[j][2cw..2cw+1] ----
        {
#pragma unroll
            for (int p = 0; p < 3; ++p) {
                int job = tid + p*1024;
                if (job < 2080) {
                    int cw = job % 65, r = job / 65;
                    int i = r & 15, h = r >> 4;
                    const _Float16* pr = sPH + (h*16 + i)*132;
                    float ax = 0.f, ay = 0.f;
#pragma unroll 8
                    for (int j = 0; j < 128; ++j) {
                        float pp = (float)pr[j];
                        h2v z2 = *(const h2v*)(comball + j*132 + 2*cw);
                        ax += pp * (float)z2.x;
                        ay += pp * (float)z2.y;
                    }
                    zb[(h*16 + i)*66 + cw] = h2v{(_Float16)ax, (_Float16)ay};
                }
            }
        }
        __syncthreads();
        // ---- P7: att[i][c'] = 0.5*sum_h vW_h^T z_h + attb ----
        {
            const h2v* VW = (const h2v*)(ws + OFF_VWB2);
            const float* attb = ws + OFF_ATTB;
#pragma unroll
            for (int p = 0; p < 2; ++p) {
                int job = tid + p*1024;
                if (job < 1040) {
                    int i = job / 65, cw = job % 65;
                    float aA = 0.f, aB = 0.f;
#pragma unroll
                    for (int h = 0; h < 2; ++h) {
                        const h2v* zr = zb + (h*16 + i)*66;
                        const h2v* Vh = VW + (h*65)*132 + 2*cw;
#pragma unroll 5
                        for (int c2 = 0; c2 < 65; ++c2) {
                            h2v z2 = zr[c2];
                            h4v w4 = *(const h4v*)(Vh + (size_t)c2*132);
                            aA = fdot2(h2v{w4.x, w4.y}, z2, aA);
                            aB = fdot2(h2v{w4.z, w4.w}, z2, aB);
                        }
                    }
                    atthh[i*66 + cw] = h2v{(_Float16)(0.5f*aA + attb[2*cw]),
                                           (_Float16)(0.5f*aB + attb[2*cw + 1])};
                }
            }
        }
        __syncthreads();
        // ---- P8: R,U gates; h1 ----
        int il = tid >> 6, o = tid & 63, n = n0 + il;
        float uu, h1;
        bool ob;
        {
            const h2v* WR = WB + ((0*128 + n)*65)*64 + o;
            const h2v* WU = WB + ((1*128 + n)*65)*64 + o;
            float aR = ws[OFF_BE + (0*128 + n)*64 + o];
            float aU = ws[OFF_BE + (1*128 + n)*64 + o];
            const h2v* ar = atthh + il*66;
#pragma unroll 5
            for (int c2 = 0; c2 < 65; ++c2) {
                h2v a2 = ar[c2];
                aR = fdot2(a2, WR[(size_t)c2*64], aR);
                aU = fdot2(a2, WU[(size_t)c2*64], aU);
            }
            float rg = 1.f/(1.f + __expf(-aR));
            uu = 1.f/(1.f + __expf(-aU));
            ob = maskL[n] > 0.f;
            float h0 = h_own[il*64 + o];
            h1 = ob ? rg*h0 : h0;
            h1L[il*66 + o] = h1;
        }
        __syncthreads();
        // ---- P8.5: candin = [x | h1] packed pairs (overlays atthh) ----
        {
#pragma unroll
            for (int p = 0; p < 2; ++p) {
                int idx = tid + p*1024;
                if (idx < 1040) {
                    int il2 = idx / 65, cw = idx % 65;
                    int c0 = 2*cw, c1 = 2*cw + 1;
                    int j = n0 + il2;
                    float v0 = (c0 < 65) ? (float)comball[j*132 + c0]
                                         : h1L[il2*66 + c0 - 65];
                    float v1 = (c1 < 65) ? (float)comball[j*132 + c1]
                             : ((c1 <= 128) ? h1L[il2*66 + c1 - 65] : 0.f);
                    candin[il2*66 + cw] = h2v{(_Float16)v0, (_Float16)v1};
                }
            }
        }
        __syncthreads();
        // ---- P9: candidate; h2; export ----
        {
            const h2v* WC = WB + ((2*128 + n)*65)*64 + o;
            float aC = ws[OFF_BE + (2*128 + n)*64 + o];
            const h2v* zr = candin + il*66;
#pragma unroll 5
            for (int c2 = 0; c2 < 65; ++c2)
                aC = fdot2(zr[c2], WC[(size_t)c2*64], aC);
            float cand = tanhf(aC);
            float h2 = ob ? (1.f - uu)*h1 + uu*cand : h1;
            h_own[il*64 + o] = h2;
            if (t == lenb - 1) out[(size_t)(b*N_ + n)*64 + o] = h2;
            if (t < T_ - 1) {
                float* Hw = Hx + (size_t)(((t + 1) & 1)*B_ + b)*N_*64 + (n0 + il)*64 + o;
                __hip_atomic_store(Hw, h2, __ATOMIC_RELAXED, __HIP_MEMORY_SCOPE_AGENT);
            }
        }
        __syncthreads();    // drains stores (compiler emits vmcnt(0) before s_barrier)
        if (t < T_ - 1 && tid == 0)
            __hip_atomic_fetch_add(&CNT[b], 1u, __ATOMIC_RELAXED, __HIP_MEMORY_SCOPE_AGENT);
    }
}

extern "C" void kernel_launch(void* const* d_in, const int* in_sizes, int n_in,
                              void* d_out, int out_size, void* d_ws, size_t ws_size,
                              hipStream_t stream) {
    (void)in_sizes; (void)n_in; (void)out_size; (void)ws_size;
    const float* obs   = (const float*)d_in[0];
    const float* mask  = (const float*)d_in[1];
    const float* avg   = (const float*)d_in[2];
    const float* plm   = (const float*)d_in[3];
    const int*   lens  = (const int*)d_in[4];
    // d_in[5] rarity_W: only the ==0 pattern of cur_adj matters -> dead values
    const float* pfW1  = (const float*)d_in[6];
    const float* pfb1  = (const float*)d_in[7];
    const float* pfW2  = (const float*)d_in[8];
    const float* pfb2  = (const float*)d_in[9];
    // d_in[10..13] pg_*: dead (softmax adjacency > 0 always)
    const float* rstW  = (const float*)d_in[14];
    const float* rstb  = (const float*)d_in[15];
    const float* updW  = (const float*)d_in[16];
    const float* updb  = (const float*)d_in[17];
    const float* candW = (const float*)d_in[18];
    const float* candb = (const float*)d_in[19];
    const float* qW    = (const float*)d_in[20];
    const float* qb    = (const float*)d_in[21];
    const float* kW    = (const float*)d_in[22];
    const float* kb    = (const float*)d_in[23];
    const float* vW    = (const float*)d_in[24];
    const float* vb    = (const float*)d_in[25];
    float* ws  = (float*)d_ws;
    float* out = (float*)d_out;

    hipMemsetAsync((char*)d_ws + (size_t)OFF_CNT*4, 0, 32*sizeof(unsigned), stream);
    hipLaunchKernelGGL(k_qv,   dim3(128), dim3(128), 0, stream, plm, pfW1, pfb1, pfW2, pfb2, ws);
    hipLaunchKernelGGL(k_weff, dim3(384), dim3(256), 0, stream, rstW, updW, candW, rstb, updb, candb, ws);
    hipLaunchKernelGGL(k_pack, dim3(64),  dim3(256), 0, stream, vW, qW, kW, vb, ws);
    hipLaunchKernelGGL(k_vto,  dim3(16),  dim3(256), 0, stream, mask, ws);

    void* args[] = {(void*)&obs, (void*)&mask, (void*)&avg, (void*)&lens,
                    (void*)&qb, (void*)&kb, (void*)&ws, (void*)&out};
    hipLaunchCooperativeKernel((void*)k_main, dim3(256), dim3(1024), args, 0, stream);
}